// Round 1
// baseline (97.756 us; speedup 1.0000x reference)
//
#include <hip/hip_runtime.h>
#include <math.h>

#define BB 4
#define LL 512
#define NROW (BB*LL)      // 2048
#define F_OP 10
#define F_EU 2
#define FIN 12
#define DD 128
#define HH 128
#define DEG 511.0f
#define SCALE 0.08838834764831845f   // 1/sqrt(128)
#define TI 32      // i-rows per adj block
#define JC 128     // j per chunk
#define NJC (LL/JC)  // 4

// ---------------- K1: embeddings + x ----------------
__global__ __launch_bounds__(128) void k_embed(
    const float* __restrict__ inputs, const float* __restrict__ coords,
    const float* __restrict__ cc, const float* __restrict__ Wc,
    const float* __restrict__ bc, const float* __restrict__ Wcc,
    const float* __restrict__ bcc,
    float* __restrict__ i_emb, float* __restrict__ ic_emb, float* __restrict__ x) {
  int row = blockIdx.x;          // 0..NROW-1
  int d = threadIdx.x;           // 0..127
  int b = row / LL;
  __shared__ float fin1[FIN], fin2[FIN];
  if (d < F_OP) {
    float v = inputs[row*F_OP + d];
    fin1[d] = v;
    fin2[d] = v - inputs[(b*LL)*F_OP + d];
  } else if (d < FIN) {
    int k = d - F_OP;
    fin1[d] = coords[row*F_EU + k];
    fin2[d] = cc[row*F_EU + k];
  }
  __syncthreads();
  float e1 = bc[d], e2 = bcc[d];
#pragma unroll
  for (int k = 0; k < FIN; ++k) {
    e1 += fin1[k] * Wc[k*DD + d];
    e2 += fin2[k] * Wcc[k*DD + d];
  }
  i_emb[row*DD + d]  = e1;
  ic_emb[row*DD + d] = e2;
  x[row*DD + d]      = e1 - e2;
}

// ---------------- generic 16-row GEMM tile: C = A @ W (+bias) ----------------
__device__ __forceinline__ void gemm_tile_body(
    const float* __restrict__ A, const float* __restrict__ W,
    const float* __restrict__ bias, float* __restrict__ C) {
  __shared__ float As[16][132];
  int t = threadIdx.x;
  int row0 = blockIdx.x * 16;
  for (int idx = t; idx < 16*32; idx += 256) {
    int r = idx >> 5, c4 = idx & 31;
    *(float4*)&As[r][c4*4] = *(const float4*)&A[(row0 + r)*DD + c4*4];
  }
  __syncthreads();
  int tx = t & 31, ty = t >> 5;      // tx: col group (4 cols), ty: row pair
  int d0 = tx * 4;
  int r0 = ty * 2;
  float acc0[4] = {0,0,0,0}, acc1[4] = {0,0,0,0};
#pragma unroll 8
  for (int k = 0; k < DD; ++k) {
    float4 w = *(const float4*)&W[k*DD + d0];
    float a0 = As[r0][k], a1 = As[r0+1][k];
    acc0[0] += a0*w.x; acc0[1] += a0*w.y; acc0[2] += a0*w.z; acc0[3] += a0*w.w;
    acc1[0] += a1*w.x; acc1[1] += a1*w.y; acc1[2] += a1*w.z; acc1[3] += a1*w.w;
  }
  float4 bv = make_float4(0.f,0.f,0.f,0.f);
  if (bias) bv = *(const float4*)&bias[d0];
  float* c0 = &C[(row0 + r0)*DD + d0];
  float* c1 = &C[(row0 + r0 + 1)*DD + d0];
  c0[0] = acc0[0]+bv.x; c0[1] = acc0[1]+bv.y; c0[2] = acc0[2]+bv.z; c0[3] = acc0[3]+bv.w;
  c1[0] = acc1[0]+bv.x; c1[1] = acc1[1]+bv.y; c1[2] = acc1[2]+bv.z; c1[3] = acc1[3]+bv.w;
}

// ---------------- K2: a, bt, a_c, b_c ----------------
__global__ __launch_bounds__(256) void k_proj4(
    const float* __restrict__ i_emb, const float* __restrict__ ic_emb,
    const float* __restrict__ Wa, const float* __restrict__ ba,
    const float* __restrict__ Wb, const float* __restrict__ bb,
    float* __restrict__ a, float* __restrict__ btm,
    float* __restrict__ a_c, float* __restrict__ b_c) {
  int m = blockIdx.y;
  const float* A = (m < 2) ? i_emb : ic_emb;
  const float* W = (m & 1) ? Wb : Wa;
  const float* bias = (m & 1) ? bb : ba;
  float* C = (m == 0) ? a : (m == 1) ? btm : (m == 2) ? a_c : b_c;
  gemm_tile_body(A, W, bias, C);
}

// ---------------- K7: P = x@W1l, Q = x@W1r ----------------
__global__ __launch_bounds__(256) void k_pq(
    const float* __restrict__ x, const float* __restrict__ W1l,
    const float* __restrict__ W1r, float* __restrict__ P, float* __restrict__ Q) {
  if (blockIdx.y == 0) gemm_tile_body(x, W1l, nullptr, P);
  else                 gemm_tile_body(x, W1r, nullptr, Q);
}

// ---------------- K3: fused adjacency: diff partials + per-row/chunk argmin ----------------
__global__ __launch_bounds__(256) void k_adj(
    const float* __restrict__ a, const float* __restrict__ btm,
    const float* __restrict__ a_c, const float* __restrict__ b_c,
    float* __restrict__ diffpart, float* __restrict__ minval, int* __restrict__ minidx) {
  int it = blockIdx.x;   // 0..LL/TI-1
  int jc = blockIdx.y;   // 0..NJC-1
  int b  = blockIdx.z;   // 0..BB-1
  int t = threadIdx.x;   // 256

  __shared__ float As[TI][DD+4], Acs[TI][DD+4];
  __shared__ float Bs[32][DD+4], Bcs[32][DD+4];

  int row_i0 = b*LL + it*TI;
  for (int idx = t; idx < TI*32; idx += 256) {
    int r = idx >> 5, c4 = idx & 31;
    *(float4*)&As[r][c4*4]  = *(const float4*)&a[(row_i0 + r)*DD + c4*4];
    *(float4*)&Acs[r][c4*4] = *(const float4*)&a_c[(row_i0 + r)*DD + c4*4];
  }

  int jl = t & 31, ig = t >> 5;   // ig: 0..7 -> rows ig*4..ig*4+3
  float mval[4] = {INFINITY, INFINITY, INFINITY, INFINITY};
  int   midx[4] = {-1,-1,-1,-1};
  float sq = 0.f;

  for (int js = 0; js < JC; js += 32) {
    __syncthreads();   // also guards As on first iteration / Bs reuse after
    int row_j0 = b*LL + jc*JC + js;
    for (int idx = t; idx < 32*32; idx += 256) {
      int r = idx >> 5, c4 = idx & 31;
      *(float4*)&Bs[r][c4*4]  = *(const float4*)&btm[(row_j0 + r)*DD + c4*4];
      *(float4*)&Bcs[r][c4*4] = *(const float4*)&b_c[(row_j0 + r)*DD + c4*4];
    }
    __syncthreads();

    float acc[4] = {0,0,0,0}, accc[4] = {0,0,0,0};
#pragma unroll 2
    for (int k = 0; k < DD; k += 4) {
      float4 bv  = *(float4*)&Bs[jl][k];
      float4 bcv = *(float4*)&Bcs[jl][k];
#pragma unroll
      for (int r = 0; r < 4; ++r) {
        float4 av  = *(float4*)&As[ig*4 + r][k];
        float4 acv = *(float4*)&Acs[ig*4 + r][k];
        acc[r]  += av.x*bv.x  + av.y*bv.y  + av.z*bv.z  + av.w*bv.w;
        accc[r] += acv.x*bcv.x + acv.y*bcv.y + acv.z*bcv.z + acv.w*bcv.w;
      }
    }
    int jg = b*LL + jc*JC + js + jl;   // global row index of neighbor j
#pragma unroll
    for (int r = 0; r < 4; ++r) {
      float adjv  = acc[r]  * SCALE;
      float adjcv = accc[r] * SCALE;
      float dd = adjv - adjcv;
      sq += dd*dd;
      if (adjv < mval[r]) { mval[r] = adjv; midx[r] = jg; }
    }
  }

  // reduce (min,argmin) across the 32 lanes sharing the same i-rows
#pragma unroll
  for (int r = 0; r < 4; ++r) {
#pragma unroll
    for (int m = 16; m > 0; m >>= 1) {
      float ov = __shfl_xor(mval[r], m);
      int   oi = __shfl_xor(midx[r], m);
      // tie: top_k excludes the LARGEST index among equal minima
      if (ov < mval[r] || (ov == mval[r] && oi > midx[r])) { mval[r] = ov; midx[r] = oi; }
    }
    if (jl == 0) {
      int n = row_i0 + ig*4 + r;     // global row 0..NROW-1
      minval[n*NJC + jc] = mval[r];
      minidx[n*NJC + jc] = midx[r];
    }
  }

  // block reduce squared-diff
  __shared__ float red[256];
  red[t] = sq;
  __syncthreads();
  for (int off = 128; off > 0; off >>= 1) {
    if (t < off) red[t] += red[t + off];
    __syncthreads();
  }
  if (t == 0) {
    int bid = (b * NJC + jc) * (LL/TI) + it;   // 0..255
    diffpart[bid] = red[0];
  }
}

// ---------------- K4: finalize diff, argmin, target_head ----------------
__global__ __launch_bounds__(256) void k_reduce(
    const float* __restrict__ diffpart, const float* __restrict__ minval,
    const int* __restrict__ minidx, const float* __restrict__ targets,
    int* __restrict__ amin, float* __restrict__ out) {
  int t = threadIdx.x;
  __shared__ float red[256];
  red[t] = diffpart[t];
  __syncthreads();
  for (int off = 128; off > 0; off >>= 1) {
    if (t < off) red[t] += red[t + off];
    __syncthreads();
  }
  if (t == 0) out[4] = red[0] / (float)(BB*LL*LL);

  for (int row = t; row < NROW; row += 256) {
    float mv = minval[row*NJC]; int mi = minidx[row*NJC];
#pragma unroll
    for (int c = 1; c < NJC; ++c) {
      float v = minval[row*NJC + c]; int i2 = minidx[row*NJC + c];
      if (v < mv || (v == mv && i2 > mi)) { mv = v; mi = i2; }
    }
    amin[row] = mi;
  }
  if (t < BB) out[5 + t] = targets[t*LL];   // targets[:,0,0]
}

// ---------------- K5: sb = (colsum_b x) @ W1l ----------------
__global__ __launch_bounds__(128) void k_sb(
    const float* __restrict__ x, const float* __restrict__ W1l, float* __restrict__ sb) {
  int b = blockIdx.x;
  int d = threadIdx.x;
  float s = 0.f;
  for (int l = 0; l < LL; ++l) s += x[(b*LL + l)*DD + d];
  __shared__ float xs[DD];
  xs[d] = s;
  __syncthreads();
  float acc = 0.f;
  for (int k = 0; k < DD; ++k) acc += xs[k] * W1l[k*DD + d];
  sb[b*DD + d] = acc;
}

// ---------------- K8: h1 = relu((sb - P[amin])/deg + b1l + Q) ----------------
__global__ __launch_bounds__(256) void k_h1(
    const float* __restrict__ P, const float* __restrict__ Q,
    const float* __restrict__ sb, const float* __restrict__ b1l,
    const int* __restrict__ amin, float* __restrict__ h1) {
  int idx = blockIdx.x*256 + threadIdx.x;   // NROW*DD threads
  int i = idx >> 7, d = idx & 127;
  int b = i >> 9;
  float v = (sb[b*DD + d] - P[amin[i]*DD + d]) * (1.0f/DEG) + b1l[d] + Q[idx];
  h1[idx] = fmaxf(v, 0.f);
}

// ---------------- K9: layer-2 at head rows only ----------------
__global__ __launch_bounds__(128) void k_final(
    const float* __restrict__ h1, const int* __restrict__ amin,
    const float* __restrict__ W2l, const float* __restrict__ b2l,
    const float* __restrict__ W2r, float* __restrict__ out) {
  int b = blockIdx.x;
  int d = threadIdx.x;
  float s = 0.f;
  for (int l = 0; l < LL; ++l) s += h1[(b*LL + l)*DD + d];
  int am = amin[b*LL];
  float agg = (s - h1[am*DD + d]) * (1.0f/DEG);
  float v = agg * W2l[d] + h1[(b*LL)*DD + d] * W2r[d];
  __shared__ float red[128];
  red[d] = v;
  __syncthreads();
  for (int off = 64; off > 0; off >>= 1) {
    if (d < off) red[d] += red[d + off];
    __syncthreads();
  }
  if (d == 0) out[b] = red[0] + b2l[0];
}

extern "C" void kernel_launch(void* const* d_in, const int* in_sizes, int n_in,
                              void* d_out, int out_size, void* d_ws, size_t ws_size,
                              hipStream_t stream) {
  const float* inputs  = (const float*)d_in[0];
  const float* coords  = (const float*)d_in[1];
  const float* targets = (const float*)d_in[2];
  const float* cc      = (const float*)d_in[3];
  // d_in[4] input_lenths: unused (all == L)
  const float* Wc  = (const float*)d_in[5];
  const float* bc  = (const float*)d_in[6];
  const float* Wcc = (const float*)d_in[7];
  const float* bcc = (const float*)d_in[8];
  const float* Wa  = (const float*)d_in[9];
  const float* ba  = (const float*)d_in[10];
  const float* Wb  = (const float*)d_in[11];
  const float* bb  = (const float*)d_in[12];
  const float* W1l = (const float*)d_in[13];
  const float* b1l = (const float*)d_in[14];
  const float* W1r = (const float*)d_in[15];
  const float* W2l = (const float*)d_in[16];
  const float* b2l = (const float*)d_in[17];
  const float* W2r = (const float*)d_in[18];
  float* out = (float*)d_out;

  float* ws = (float*)d_ws;
  float* i_emb  = ws;
  float* ic_emb = ws + 1*NROW*DD;
  float* x      = ws + 2*NROW*DD;
  float* a      = ws + 3*NROW*DD;
  float* btm    = ws + 4*NROW*DD;
  float* a_c    = ws + 5*NROW*DD;
  float* b_c    = ws + 6*NROW*DD;
  float* P  = i_emb;    // reuse: i_emb dead after k_proj4
  float* Q  = ic_emb;   // reuse: ic_emb dead after k_proj4
  float* h1 = a;        // reuse: a dead after k_adj
  float* sb       = ws + 7*NROW*DD;            // BB*DD
  float* diffpart = sb + BB*DD;                // 256
  float* minval   = diffpart + 256;            // NROW*NJC
  int*   minidx   = (int*)(minval + NROW*NJC); // NROW*NJC
  int*   amin     = minidx + NROW*NJC;         // NROW

  k_embed <<<NROW, DD, 0, stream>>>(inputs, coords, cc, Wc, bc, Wcc, bcc, i_emb, ic_emb, x);
  k_proj4 <<<dim3(NROW/16, 4), 256, 0, stream>>>(i_emb, ic_emb, Wa, ba, Wb, bb, a, btm, a_c, b_c);
  k_adj   <<<dim3(LL/TI, NJC, BB), 256, 0, stream>>>(a, btm, a_c, b_c, diffpart, minval, minidx);
  k_reduce<<<1, 256, 0, stream>>>(diffpart, minval, minidx, targets, amin, out);
  k_sb    <<<BB, DD, 0, stream>>>(x, W1l, sb);
  k_pq    <<<dim3(NROW/16, 2), 256, 0, stream>>>(x, W1l, W1r, P, Q);
  k_h1    <<<NROW*DD/256, 256, 0, stream>>>(P, Q, sb, b1l, amin, h1);
  k_final <<<BB, DD, 0, stream>>>(h1, amin, W2l, b2l, W2r, out);
}

// Round 2
// 42.032 us; speedup vs baseline: 2.3257x; 2.3257x over previous
//
#include <hip/hip_runtime.h>
#include <math.h>

#define BB 4
#define LL 512
#define NROW (BB*LL)      // 2048
#define DD 128
#define DEG 511.0f
#define SCALE 0.08838834764831845f   // 1/sqrt(128)

typedef short bf16x8 __attribute__((ext_vector_type(8)));
typedef float f32x4 __attribute__((ext_vector_type(4)));

static __device__ __forceinline__ ushort f2bf(float f) {
  unsigned u = __float_as_uint(f);
  u = (u + 0x7fffu + ((u >> 16) & 1u)) >> 16;   // RNE
  return (ushort)u;
}

// ---------------- K1: embed + 6 projections + colsum(x) partials ----------------
// blockIdx.y = m: 0 -> a,bt (bf16) from i_emb; 1 -> a_c,b_c (bf16) from ic_emb;
//                 2 -> P,Q (f32) from x, plus colsum(x) partial.
__global__ __launch_bounds__(256) void k_front(
    const float* __restrict__ inputs, const float* __restrict__ coords,
    const float* __restrict__ cc,
    const float* __restrict__ Wc, const float* __restrict__ bc,
    const float* __restrict__ Wcc, const float* __restrict__ bcc,
    const float* __restrict__ Wa, const float* __restrict__ ba,
    const float* __restrict__ Wb, const float* __restrict__ bb,
    const float* __restrict__ W1l, const float* __restrict__ W1r,
    ushort* __restrict__ bfA, ushort* __restrict__ bfB,
    ushort* __restrict__ bfAc, ushort* __restrict__ bfBc,
    float* __restrict__ P, float* __restrict__ Q,
    float* __restrict__ xpart) {
  int bx = blockIdx.x, m = blockIdx.y;
  int t = threadIdx.x;
  int row0 = bx * 16;
  int b = bx >> 5;
  __shared__ float fin1[16][12], fin2[16][12];
  __shared__ float Es[16][132];
  __shared__ float cs[2][128];
  if (t < 192) {
    int r = t / 12, k = t % 12;
    int row = row0 + r;
    float v1, v2;
    if (k < 10) {
      float v = inputs[row*10 + k];
      v1 = v;
      v2 = v - inputs[(b*LL)*10 + k];
    } else {
      v1 = coords[row*2 + (k-10)];
      v2 = cc[row*2 + (k-10)];
    }
    fin1[r][k] = v1;
    fin2[r][k] = v2;
  }
  __syncthreads();
  for (int it = 0; it < 8; ++it) {
    int idx = t + it*256;
    int r = idx >> 7, d = idx & 127;
    float e;
    if (m == 0) {
      e = bc[d];
#pragma unroll
      for (int k = 0; k < 12; ++k) e += fin1[r][k] * Wc[k*DD + d];
    } else if (m == 1) {
      e = bcc[d];
#pragma unroll
      for (int k = 0; k < 12; ++k) e += fin2[r][k] * Wcc[k*DD + d];
    } else {
      float e1 = bc[d], e2 = bcc[d];
#pragma unroll
      for (int k = 0; k < 12; ++k) {
        e1 += fin1[r][k] * Wc[k*DD + d];
        e2 += fin2[r][k] * Wcc[k*DD + d];
      }
      e = e1 - e2;
    }
    Es[r][d] = e;
  }
  __syncthreads();
  if (m == 2) {   // colsum(x) partial over these 16 rows
    int d = t & 127, h = t >> 7;
    float s = 0.f;
#pragma unroll
    for (int r = 0; r < 8; ++r) s += Es[h*8 + r][d];
    cs[h][d] = s;
    __syncthreads();
    if (h == 0) xpart[bx*DD + d] = cs[0][d] + cs[1][d];
  }
  const float* U = (m == 2) ? W1l : Wa;
  const float* V = (m == 2) ? W1r : Wb;
  int tx = t & 31, ty = t >> 5;
  int d0 = tx*4, r0 = ty*2;
  float aU0[4]={0,0,0,0}, aU1[4]={0,0,0,0}, aV0[4]={0,0,0,0}, aV1[4]={0,0,0,0};
#pragma unroll 4
  for (int k = 0; k < DD; ++k) {
    float4 u = *(const float4*)&U[k*DD + d0];
    float4 v = *(const float4*)&V[k*DD + d0];
    float e0 = Es[r0][k], e1 = Es[r0+1][k];
    aU0[0]+=e0*u.x; aU0[1]+=e0*u.y; aU0[2]+=e0*u.z; aU0[3]+=e0*u.w;
    aU1[0]+=e1*u.x; aU1[1]+=e1*u.y; aU1[2]+=e1*u.z; aU1[3]+=e1*u.w;
    aV0[0]+=e0*v.x; aV0[1]+=e0*v.y; aV0[2]+=e0*v.z; aV0[3]+=e0*v.w;
    aV1[0]+=e1*v.x; aV1[1]+=e1*v.y; aV1[2]+=e1*v.z; aV1[3]+=e1*v.w;
  }
  if (m < 2) {
    float4 bu = *(const float4*)&ba[d0];
    float4 bw = *(const float4*)&bb[d0];
    ushort* dU = (m == 0) ? bfA : bfAc;
    ushort* dV = (m == 0) ? bfB : bfBc;
    ushort4 o;
    o = make_ushort4(f2bf(aU0[0]+bu.x), f2bf(aU0[1]+bu.y), f2bf(aU0[2]+bu.z), f2bf(aU0[3]+bu.w));
    *(ushort4*)&dU[(row0+r0)*DD + d0] = o;
    o = make_ushort4(f2bf(aU1[0]+bu.x), f2bf(aU1[1]+bu.y), f2bf(aU1[2]+bu.z), f2bf(aU1[3]+bu.w));
    *(ushort4*)&dU[(row0+r0+1)*DD + d0] = o;
    o = make_ushort4(f2bf(aV0[0]+bw.x), f2bf(aV0[1]+bw.y), f2bf(aV0[2]+bw.z), f2bf(aV0[3]+bw.w));
    *(ushort4*)&dV[(row0+r0)*DD + d0] = o;
    o = make_ushort4(f2bf(aV1[0]+bw.x), f2bf(aV1[1]+bw.y), f2bf(aV1[2]+bw.z), f2bf(aV1[3]+bw.w));
    *(ushort4*)&dV[(row0+r0+1)*DD + d0] = o;
  } else {
    *(float4*)&P[(row0+r0)*DD + d0]   = make_float4(aU0[0],aU0[1],aU0[2],aU0[3]);
    *(float4*)&P[(row0+r0+1)*DD + d0] = make_float4(aU1[0],aU1[1],aU1[2],aU1[3]);
    *(float4*)&Q[(row0+r0)*DD + d0]   = make_float4(aV0[0],aV0[1],aV0[2],aV0[3]);
    *(float4*)&Q[(row0+r0+1)*DD + d0] = make_float4(aV1[0],aV1[1],aV1[2],aV1[3]);
  }
}

// ---------------- K2: MFMA adjacency: diff partials + per-row/chunk argmin ----------------
__global__ __launch_bounds__(256, 2) void k_adj(
    const ushort* __restrict__ bfA, const ushort* __restrict__ bfB,
    const ushort* __restrict__ bfAc, const ushort* __restrict__ bfBc,
    float* __restrict__ diffpart, float* __restrict__ minval, int* __restrict__ minidx) {
  __shared__ ushort As[64][136], Acs[64][136], Bs[64][136], Bcs[64][136];
  __shared__ float red[256];
  int t = threadIdx.x;
  int ix = blockIdx.x, jy = blockIdx.y, b = blockIdx.z;
  int i0 = b*LL + ix*64, j0 = b*LL + jy*64;
  for (int it = 0; it < 4; ++it) {
    int chunk = t + it*256;
    int row = chunk >> 4, c = chunk & 15;
    *(uint4*)&As[row][c*8]  = *(const uint4*)&bfA[(size_t)(i0+row)*DD + c*8];
    *(uint4*)&Acs[row][c*8] = *(const uint4*)&bfAc[(size_t)(i0+row)*DD + c*8];
    *(uint4*)&Bs[row][c*8]  = *(const uint4*)&bfB[(size_t)(j0+row)*DD + c*8];
    *(uint4*)&Bcs[row][c*8] = *(const uint4*)&bfBc[(size_t)(j0+row)*DD + c*8];
  }
  __syncthreads();
  int wave = t >> 6, lane = t & 63;
  int rA = wave*16 + (lane & 15);
  int koff = (lane >> 4) * 8;
  bf16x8 av[4], acv[4];
#pragma unroll
  for (int ks = 0; ks < 4; ++ks) {
    av[ks]  = *(const bf16x8*)&As[rA][ks*32 + koff];
    acv[ks] = *(const bf16x8*)&Acs[rA][ks*32 + koff];
  }
  f32x4 zf = {0.f, 0.f, 0.f, 0.f};
  f32x4 acc[4], accc[4];
#pragma unroll
  for (int jt = 0; jt < 4; ++jt) { acc[jt] = zf; accc[jt] = zf; }
#pragma unroll
  for (int ks = 0; ks < 4; ++ks) {
#pragma unroll
    for (int jt = 0; jt < 4; ++jt) {
      bf16x8 bv  = *(const bf16x8*)&Bs[jt*16 + (lane&15)][ks*32 + koff];
      bf16x8 bcv = *(const bf16x8*)&Bcs[jt*16 + (lane&15)][ks*32 + koff];
      acc[jt]  = __builtin_amdgcn_mfma_f32_16x16x32_bf16(av[ks],  bv,  acc[jt],  0,0,0);
      accc[jt] = __builtin_amdgcn_mfma_f32_16x16x32_bf16(acv[ks], bcv, accc[jt], 0,0,0);
    }
  }
  // epilogue: C row = (lane>>4)*4 + reg, col = lane&15 (within wave's 16 rows x jt*16 cols)
  int g = lane >> 4, c = lane & 15;
  float sq = 0.f;
#pragma unroll
  for (int r = 0; r < 4; ++r) {
    float mn = INFINITY; int mi = -1;
#pragma unroll
    for (int jt = 0; jt < 4; ++jt) {
      float v  = acc[jt][r]  * SCALE;
      float vc = accc[jt][r] * SCALE;
      float d = v - vc;
      sq += d*d;
      int j = j0 + jt*16 + c;
      if (v < mn || (v == mn && j > mi)) { mn = v; mi = j; }
    }
#pragma unroll
    for (int msk = 1; msk < 16; msk <<= 1) {
      float ov = __shfl_xor(mn, msk);
      int   oi = __shfl_xor(mi, msk);
      if (ov < mn || (ov == mn && oi > mi)) { mn = ov; mi = oi; }
    }
    if (c == 0) {
      int gi = i0 + wave*16 + g*4 + r;
      minval[gi*8 + jy] = mn;
      minidx[gi*8 + jy] = mi;
    }
  }
  red[t] = sq;
  __syncthreads();
  for (int off = 128; off > 0; off >>= 1) {
    if (t < off) red[t] += red[t+off];
    __syncthreads();
  }
  if (t == 0) diffpart[(b*8 + jy)*8 + ix] = red[0];
}

// ---------------- K3: diff finalize + argmin finalize + sb GEMV + targets ----------------
__global__ __launch_bounds__(256) void k_mid(
    const float* __restrict__ diffpart, const float* __restrict__ minval,
    const int* __restrict__ minidx, const float* __restrict__ targets,
    const float* __restrict__ xpart, const float* __restrict__ W1l,
    int* __restrict__ amin, float* __restrict__ sb, float* __restrict__ out) {
  int bz = blockIdx.x, t = threadIdx.x;
  __shared__ float red[256];
  __shared__ float cs[2][128];
  __shared__ float xs[128];
  if (bz < 4) {
    if (bz == 0) {
      red[t] = diffpart[t];
      __syncthreads();
      for (int off = 128; off > 0; off >>= 1) {
        if (t < off) red[t] += red[t+off];
        __syncthreads();
      }
      if (t == 0) out[4] = red[0] / (float)((float)BB*LL*LL);
      if (t < 4) out[5+t] = targets[t*LL];
    }
    for (int it = 0; it < 2; ++it) {
      int row = bz*LL + it*256 + t;
      float mv = minval[row*8]; int mi = minidx[row*8];
#pragma unroll
      for (int ch = 1; ch < 8; ++ch) {
        float v = minval[row*8+ch]; int i2 = minidx[row*8+ch];
        if (v < mv || (v == mv && i2 > mi)) { mv = v; mi = i2; }
      }
      amin[row] = mi;
    }
  } else {
    int b = bz - 4;
    int d = t & 127, h = t >> 7;
    float s = 0.f;
    for (int i = 0; i < 16; ++i) s += xpart[(b*32 + h*16 + i)*DD + d];
    cs[h][d] = s;
    __syncthreads();
    if (h == 0) xs[d] = cs[0][d] + cs[1][d];
    __syncthreads();
    float acc2 = 0.f;
    for (int k = 0; k < 64; ++k) acc2 += xs[h*64 + k] * W1l[(h*64 + k)*DD + d];
    cs[h][d] = acc2;
    __syncthreads();
    if (h == 0) sb[b*DD + d] = cs[0][d] + cs[1][d];
  }
}

// ---------------- K4: h1 + colsum(h1) partials ----------------
__global__ __launch_bounds__(256) void k_h1(
    const float* __restrict__ P, const float* __restrict__ Q,
    const float* __restrict__ sb, const float* __restrict__ b1l,
    const int* __restrict__ amin, float* __restrict__ h1,
    float* __restrict__ h1part) {
  int bx = blockIdx.x, t = threadIdx.x;
  int d = t & 127, h = t >> 7;
  int b = bx >> 4;
  float base = sb[b*DD + d] * (1.0f/DEG) + b1l[d];
  float ps = 0.f;
  for (int rr = 0; rr < 16; ++rr) {
    int i = bx*32 + h*16 + rr;
    int am = amin[i];
    float v = base - P[am*DD + d] * (1.0f/DEG) + Q[i*DD + d];
    v = fmaxf(v, 0.f);
    h1[i*DD + d] = v;
    ps += v;
  }
  __shared__ float cs[2][128];
  cs[h][d] = ps;
  __syncthreads();
  if (h == 0) h1part[bx*DD + d] = cs[0][d] + cs[1][d];
}

// ---------------- K5: layer-2 at head rows ----------------
__global__ __launch_bounds__(128) void k_final(
    const float* __restrict__ h1, const float* __restrict__ h1part,
    const int* __restrict__ amin,
    const float* __restrict__ W2l, const float* __restrict__ b2l,
    const float* __restrict__ W2r, float* __restrict__ out) {
  int b = blockIdx.x, d = threadIdx.x;
  float s = 0.f;
#pragma unroll
  for (int p = 0; p < 16; ++p) s += h1part[(b*16 + p)*DD + d];
  int am = amin[b*LL];
  float agg = (s - h1[am*DD + d]) * (1.0f/DEG);
  float v = agg * W2l[d] + h1[(b*LL)*DD + d] * W2r[d];
  __shared__ float red[128];
  red[d] = v;
  __syncthreads();
  for (int off = 64; off > 0; off >>= 1) {
    if (d < off) red[d] += red[d+off];
    __syncthreads();
  }
  if (d == 0) out[b] = red[0] + b2l[0];
}

extern "C" void kernel_launch(void* const* d_in, const int* in_sizes, int n_in,
                              void* d_out, int out_size, void* d_ws, size_t ws_size,
                              hipStream_t stream) {
  const float* inputs  = (const float*)d_in[0];
  const float* coords  = (const float*)d_in[1];
  const float* targets = (const float*)d_in[2];
  const float* cc      = (const float*)d_in[3];
  const float* Wc  = (const float*)d_in[5];
  const float* bc  = (const float*)d_in[6];
  const float* Wcc = (const float*)d_in[7];
  const float* bcc = (const float*)d_in[8];
  const float* Wa  = (const float*)d_in[9];
  const float* ba  = (const float*)d_in[10];
  const float* Wb  = (const float*)d_in[11];
  const float* bb  = (const float*)d_in[12];
  const float* W1l = (const float*)d_in[13];
  const float* b1l = (const float*)d_in[14];
  const float* W1r = (const float*)d_in[15];
  const float* W2l = (const float*)d_in[16];
  const float* b2l = (const float*)d_in[17];
  const float* W2r = (const float*)d_in[18];
  float* out = (float*)d_out;

  float* ws = (float*)d_ws;
  float* P  = ws;
  float* Q  = ws + (size_t)NROW*DD;
  float* h1 = ws + (size_t)2*NROW*DD;
  ushort* bfA  = (ushort*)(ws + (size_t)3*NROW*DD);
  ushort* bfB  = bfA  + (size_t)NROW*DD;
  ushort* bfAc = bfB  + (size_t)NROW*DD;
  ushort* bfBc = bfAc + (size_t)NROW*DD;
  float* xpart    = ws + (size_t)5*NROW*DD;   // 128*128
  float* h1part   = xpart + 128*DD;           // 64*128
  float* sb       = h1part + 64*DD;           // 4*128
  float* diffpart = sb + 4*DD;                // 256
  float* minval   = diffpart + 256;           // NROW*8
  int*   minidx   = (int*)(minval + (size_t)NROW*8);
  int*   amin     = minidx + (size_t)NROW*8;

  k_front<<<dim3(128, 3), 256, 0, stream>>>(inputs, coords, cc, Wc, bc, Wcc, bcc,
                                            Wa, ba, Wb, bb, W1l, W1r,
                                            bfA, bfB, bfAc, bfBc, P, Q, xpart);
  k_adj  <<<dim3(8, 8, 4), 256, 0, stream>>>(bfA, bfB, bfAc, bfBc, diffpart, minval, minidx);
  k_mid  <<<8, 256, 0, stream>>>(diffpart, minval, minidx, targets, xpart, W1l, amin, sb, out);
  k_h1   <<<64, 256, 0, stream>>>(P, Q, sb, b1l, amin, h1, h1part);
  k_final<<<4, 128, 0, stream>>>(h1, h1part, amin, W2l, b2l, W2r, out);
}